// Round 1
// baseline (774.301 us; speedup 1.0000x reference)
//
#include <hip/hip_runtime.h>
#include <hip/hip_cooperative_groups.h>

// TAGConv K=2, D=128. Round 8: dispatch-count reduction (6 -> 2) via one
// cooperative kernel {zero, mega, bucket_csr, spmm1, spmm2} + gemm.
// Round-7 counters: spmm 62.5us x2; residual ~60-70us is inter-dispatch gap
// (round-6 measured ~11us/dispatch). grid.sync() replaces 4 gaps.
// Co-residency surgery:
//  - bucket_csr: LDS lcsr dump (64KB -> 2 blk/CU) replaced by direct global
//    scatter of csr (6.4MB, L2-absorbed) so fused LDS stays ~7KB.
//  - binscatter EPT 16->8 so VGPR fits __launch_bounds__(256,8) (<=64 VGPR,
//    8 blk/CU, 2048-block cooperative grid; spmm phase keeps occupancy).
//  - gCursor zeroed in phase 0 (memset dispatch deleted).
// gemm stays separate: its ~170 VGPR B-in-register scheme would cap fused
// occupancy at ~12 waves/CU and cost more than one gap saves.
// Fallback: if cooperative launch fails, original 6-dispatch pipeline.

#define D 128
#define TPB 256
#define GEMM_GRID 768

#define BSH 9
#define BSZ 512              // nodes per bucket
#define NBMAX 256            // max buckets
#define EPT 8                // edges per thread in binscatter (16->8 for VGPR)
#define CH (TPB * EPT)       // 2048 edges per chunk
#define LCAP 16384           // fixed per-bucket region

namespace cg = cooperative_groups;

typedef __attribute__((ext_vector_type(8))) short short8;
typedef __attribute__((ext_vector_type(4))) float f32x4;

__device__ __forceinline__ ushort f2bf(float f) {
    unsigned u = __float_as_uint(f);
    u += 0x7fff + ((u >> 16) & 1);      // round-to-nearest-even
    return (ushort)(u >> 16);
}
__device__ __forceinline__ unsigned pack2bf(float x, float y) {
    return (unsigned)f2bf(x) | ((unsigned)f2bf(y) << 16);
}
__device__ __forceinline__ float bf_lo(unsigned v) { return __uint_as_float(v << 16); }
__device__ __forceinline__ float bf_hi(unsigned v) { return __uint_as_float(v & 0xffff0000u); }

// ---------------- phase bodies (shared by fused + fallback kernels) --------

// mega: binscatter || prescale || wconv, selected by chunk id.
__device__ __forceinline__ void mega_body(
    int bid, int t,
    const int* __restrict__ src, const int* __restrict__ dst,
    int* __restrict__ gCursor, unsigned* __restrict__ tmp,
    const float* __restrict__ feat, unsigned* __restrict__ featb,
    const float* __restrict__ W, ushort* __restrict__ Wb,
    int e, int n, int nbin, int npre) {
    __shared__ int hist[NBMAX];
    __shared__ int cellBase[NBMAX];
    if (bid < nbin) {
        hist[t] = 0;
        __syncthreads();
        int base = bid * CH;
        int b[EPT]; unsigned pk[EPT]; int r[EPT];
#pragma unroll
        for (int k = 0; k < EPT; ++k) {
            int i = base + k * TPB + t;
            b[k] = -1;
            if (i < e) {
                int d = dst[i];
                b[k] = d >> BSH;
                pk[k] = ((unsigned)src[i] << BSH) | (unsigned)(d & (BSZ - 1));
                r[k] = atomicAdd(&hist[b[k]], 1);
            }
        }
        __syncthreads();
        int h = hist[t];
        cellBase[t] = h ? t * LCAP + atomicAdd(&gCursor[t], h) : 0;
        __syncthreads();
#pragma unroll
        for (int k = 0; k < EPT; ++k)
            if (b[k] >= 0) tmp[cellBase[b[k]] + r[k]] = pk[k];
        __syncthreads();            // LDS reuse guard (block-stride loop)
    } else if (bid < nbin + npre) {
        int gid = (bid - nbin) * TPB + t;
        int node = gid >> 6, c = gid & 63;
        if (node < n) {
            float2 f = ((const float2*)(feat + (size_t)node * D))[c];
            featb[(size_t)node * 64 + c] = pack2bf(f.x, f.y);
        }
    } else {
        int i = ((bid - nbin - npre) * TPB + t) * 4;   // D*384 = 49152 elems
        float4 w = *(const float4*)(W + i);
        ushort4 o;
        o.x = f2bf(w.x); o.y = f2bf(w.y); o.z = f2bf(w.z); o.w = f2bf(w.w);
        *(ushort4*)(Wb + i) = o;
    }
}

// per-bucket CSR: LDS histogram + scan, then direct global scatter (no lcsr).
__device__ __forceinline__ void bucket_body(
    int bkt, int t,
    const unsigned* __restrict__ tmp, const int* __restrict__ gCursor,
    int2* __restrict__ rsdeg, float* __restrict__ norm, int* __restrict__ csr,
    int n) {
    __shared__ int cnt[BSZ];
    __shared__ int off[BSZ];
    __shared__ int pr[TPB];
    int beg = bkt * LCAP;
    int m = gCursor[bkt];
    int end = beg + m;
    cnt[t] = 0; cnt[t + TPB] = 0;
    __syncthreads();
    for (int i = beg + t; i < end; i += TPB)
        atomicAdd(&cnt[tmp[i] & (BSZ - 1)], 1);
    __syncthreads();
    // exclusive scan of cnt[512] via 256-pair Hillis-Steele
    int c0 = cnt[2 * t], c1 = cnt[2 * t + 1];
    int own = c0 + c1;
    pr[t] = own;
    __syncthreads();
    for (int o = 1; o < TPB; o <<= 1) {
        int x = (t >= o) ? pr[t - o] : 0;
        __syncthreads();
        pr[t] += x;
        __syncthreads();
    }
    int ex = pr[t] - own;
    off[2 * t] = ex;
    off[2 * t + 1] = ex + c0;
    __syncthreads();
    cnt[t] = 0; cnt[t + TPB] = 0;          // reuse as rank counters
    __syncthreads();
    for (int i = beg + t; i < end; i += TPB) {
        unsigned v = tmp[i];
        int l = v & (BSZ - 1);
        int r = atomicAdd(&cnt[l], 1);
        int idx = off[l] + r;
        if (idx < LCAP) csr[beg + idx] = (int)(v >> BSH);
    }
    __syncthreads();
    int node0 = bkt << BSH;
    for (int l = t; l < BSZ; l += TPB) {
        int node = node0 + l;
        if (node < n) {
            rsdeg[node] = make_int2(beg + off[l], cnt[l]);
            norm[node] = rsqrtf((float)cnt[l]);
        }
    }
    __syncthreads();                        // LDS reuse guard
}

// SpMM: hout[v] = bf16( norm[v] * sum_u norm[u]*hin[u] ), wave per node,
// grid-stride over nodes. Quarter-wave q handles edge beg+j*4+q, c=lane&15
// handles a 16B column chunk.
__device__ __forceinline__ void spmm_body(
    const uint4* __restrict__ hin4, const int2* __restrict__ rsdeg,
    const int* __restrict__ csr, const float* __restrict__ norm,
    unsigned* __restrict__ hout, int n) {
    int gw = (int)((blockIdx.x * TPB + threadIdx.x) >> 6);
    int nw = (int)((gridDim.x * TPB) >> 6);
    int lane = threadIdx.x & 63;
    int q = lane >> 4;
    int c = lane & 15;
    for (int w = gw; w < n; w += nw) {
        int2 rd = rsdeg[w];
        int beg = rd.x, end = rd.x + rd.y;
        float acc[8] = {};
#pragma unroll 4
        for (int j = beg + q; j < end; j += 4) {
            int u = csr[j];
            float s = norm[u];
            uint4 v = hin4[(u << 4) + c];
            acc[0] = fmaf(s, bf_lo(v.x), acc[0]);
            acc[1] = fmaf(s, bf_hi(v.x), acc[1]);
            acc[2] = fmaf(s, bf_lo(v.y), acc[2]);
            acc[3] = fmaf(s, bf_hi(v.y), acc[3]);
            acc[4] = fmaf(s, bf_lo(v.z), acc[4]);
            acc[5] = fmaf(s, bf_hi(v.z), acc[5]);
            acc[6] = fmaf(s, bf_lo(v.w), acc[6]);
            acc[7] = fmaf(s, bf_hi(v.w), acc[7]);
        }
#pragma unroll
        for (int k = 0; k < 8; ++k) {
            acc[k] += __shfl_xor(acc[k], 16, 64);
            acc[k] += __shfl_xor(acc[k], 32, 64);
        }
        if (q == 0) {
            float nv = norm[w];
            uint4 r;
            r.x = pack2bf(acc[0] * nv, acc[1] * nv);
            r.y = pack2bf(acc[2] * nv, acc[3] * nv);
            r.z = pack2bf(acc[4] * nv, acc[5] * nv);
            r.w = pack2bf(acc[6] * nv, acc[7] * nv);
            *(uint4*)(hout + (size_t)w * 64 + c * 4) = r;
        }
    }
}

// ---------------- fused cooperative kernel ----------------
__global__ __launch_bounds__(TPB, 8) void fused_kernel(
    const int* __restrict__ src, const int* __restrict__ dst,
    int* __restrict__ gCursor, unsigned* __restrict__ tmp,
    const float* __restrict__ feat, unsigned* __restrict__ featb,
    const float* __restrict__ W, ushort* __restrict__ Wb,
    int2* __restrict__ rsdeg, float* __restrict__ norm, int* __restrict__ csr,
    unsigned* __restrict__ h1b, unsigned* __restrict__ h2b,
    int e, int n, int nbin, int npre, int nwcv, int nb) {
    cg::grid_group grid = cg::this_grid();
    int t = threadIdx.x;

    // phase 0: zero bucket cursors
    if (blockIdx.x == 0 && t < NBMAX) gCursor[t] = 0;
    grid.sync();

    // phase 1: binscatter || prescale || wconv
    int total1 = nbin + npre + nwcv;
    for (int bid = blockIdx.x; bid < total1; bid += gridDim.x)
        mega_body(bid, t, src, dst, gCursor, tmp, feat, featb, W, Wb,
                  e, n, nbin, npre);
    grid.sync();

    // phase 2: per-bucket CSR
    for (int bkt = blockIdx.x; bkt < nb; bkt += gridDim.x)
        bucket_body(bkt, t, tmp, gCursor, rsdeg, norm, csr, n);
    grid.sync();

    // phase 3: hop 1
    spmm_body((const uint4*)featb, rsdeg, csr, norm, h1b, n);
    grid.sync();

    // phase 4: hop 2
    spmm_body((const uint4*)h1b, rsdeg, csr, norm, h2b, n);
}

// ---------------- fallback wrappers (non-cooperative path) ----------------
__global__ __launch_bounds__(TPB) void mega_kernel(
    const int* __restrict__ src, const int* __restrict__ dst,
    int* __restrict__ gCursor, unsigned* __restrict__ tmp,
    const float* __restrict__ feat, unsigned* __restrict__ featb,
    const float* __restrict__ W, ushort* __restrict__ Wb,
    int e, int n, int nbin, int npre) {
    mega_body(blockIdx.x, threadIdx.x, src, dst, gCursor, tmp, feat, featb,
              W, Wb, e, n, nbin, npre);
}

__global__ __launch_bounds__(TPB) void bucket_csr_kernel(
    const unsigned* __restrict__ tmp, const int* __restrict__ gCursor,
    int2* __restrict__ rsdeg, float* __restrict__ norm, int* __restrict__ csr,
    int n) {
    bucket_body(blockIdx.x, threadIdx.x, tmp, gCursor, rsdeg, norm, csr, n);
}

__global__ __launch_bounds__(TPB) void spmm_kernel(
    const uint4* __restrict__ hin4, const int2* __restrict__ rsdeg,
    const int* __restrict__ csr, const float* __restrict__ norm,
    unsigned* __restrict__ hout, int n) {
    spmm_body(hin4, rsdeg, csr, norm, hout, n);
}

// ---------------- GEMM: out[n][128] = [featb|h1b|h2b] @ Wb^T + b -----------
// 4 waves/block; wave owns a 32-col W slice in registers (24 bf16 frags).
// A frag: row m=lane&15, k=(lane>>4)*8+j.  C/D: col=lane&15, row=(lane>>4)*4+reg.
__global__ __launch_bounds__(TPB) void gemm_mfma_kernel(
    const ushort* __restrict__ featb, const ushort* __restrict__ h1b,
    const ushort* __restrict__ h2b, const ushort* __restrict__ Wb,
    const float* __restrict__ bias, float* __restrict__ out, int n, int ntiles) {
    int lane = threadIdx.x & 63;
    int wave = threadIdx.x >> 6;
    int m = lane & 15, q = lane >> 4;

    short8 b[12][2];
#pragma unroll
    for (int ks = 0; ks < 12; ++ks)
#pragma unroll
        for (int t = 0; t < 2; ++t)
            b[ks][t] = *(const short8*)(Wb + (size_t)(wave * 32 + t * 16 + m) * 384
                                        + ks * 32 + q * 8);
    float bv0 = bias[wave * 32 + m];
    float bv1 = bias[wave * 32 + 16 + m];

    const ushort* srcs[3] = {featb, h1b, h2b};

    for (int tile = blockIdx.x; tile < ntiles; tile += gridDim.x) {
        int row = tile * 16 + m;
        bool va = row < n;
        size_t arow = (size_t)row * D;
        short8 a[12] = {};
        if (va) {
#pragma unroll
            for (int ks = 0; ks < 12; ++ks)
                a[ks] = *(const short8*)(srcs[ks >> 2] + arow + (ks & 3) * 32 + q * 8);
        }
        f32x4 acc0 = {}, acc1 = {};
#pragma unroll
        for (int ks = 0; ks < 12; ++ks) {
            acc0 = __builtin_amdgcn_mfma_f32_16x16x32_bf16(a[ks], b[ks][0], acc0, 0, 0, 0);
            acc1 = __builtin_amdgcn_mfma_f32_16x16x32_bf16(a[ks], b[ks][1], acc1, 0, 0, 0);
        }
        int r0 = tile * 16 + q * 4;
#pragma unroll
        for (int r = 0; r < 4; ++r) {
            int rw = r0 + r;
            if (rw < n) {
                size_t o = (size_t)rw * D + wave * 32 + m;
                out[o] = acc0[r] + bv0;
                out[o + 16] = acc1[r] + bv1;
            }
        }
    }
}

extern "C" void kernel_launch(void* const* d_in, const int* in_sizes, int n_in,
                              void* d_out, int out_size, void* d_ws, size_t ws_size,
                              hipStream_t stream) {
    const float* feat = (const float*)d_in[0];
    const int* src    = (const int*)d_in[1];
    const int* dst    = (const int*)d_in[2];
    const float* W    = (const float*)d_in[3];
    const float* bias = (const float*)d_in[4];
    float* out        = (float*)d_out;

    int N = in_sizes[0] / D;        // 100000
    int E = in_sizes[1];            // 1600000
    int NB = (N + BSZ - 1) >> BSH;  // 196

    char* ws = (char*)d_ws;
    size_t off = 0;
    auto bump = [&](size_t bytes) {
        char* p = ws + off;
        off += (bytes + 255) & ~(size_t)255;
        return p;
    };
    int* gCursor     = (int*)bump((size_t)NBMAX * 4);
    float* norm      = (float*)bump((size_t)N * 4);
    int2* rsdeg      = (int2*)bump((size_t)N * 8);
    unsigned* tmp    = (unsigned*)bump((size_t)NB * LCAP * 4);   // 12.85 MB
    int* csr         = (int*)bump((size_t)NB * LCAP * 4);        // 12.85 MB
    unsigned* featb  = (unsigned*)bump((size_t)N * 64 * 4);      // bf16x2 rows
    unsigned* h1b    = (unsigned*)bump((size_t)N * 64 * 4);
    unsigned* h2b    = (unsigned*)bump((size_t)N * 64 * 4);
    ushort* Wb       = (ushort*)bump((size_t)D * 384 * 2);
    (void)ws_size;

    int nbin = (E + CH - 1) / CH;                // 782
    int npre = (N * 64 + TPB - 1) / TPB;         // 25000
    int nwcv = (D * 384 / 4 + TPB - 1) / TPB;    // 48

    // mode: 0 = untried, 1 = cooperative, 2 = fallback
    static int s_mode = 0;
    static int s_grid = 0;
    if (s_mode == 0) {
        int bpc = 0;
        if (hipOccupancyMaxActiveBlocksPerMultiprocessor(&bpc, fused_kernel,
                                                         TPB, 0) != hipSuccess ||
            bpc < 1)
            bpc = 1;
        int g = bpc * 256;                       // 256 CUs on MI355X
        if (g > 4096) g = 4096;
        s_grid = g;
    }

    if (s_mode != 2) {
        void* args[] = {&src, &dst, &gCursor, &tmp, &feat, &featb, &W, &Wb,
                        &rsdeg, &norm, &csr, &h1b, &h2b,
                        &E, &N, &nbin, &npre, &nwcv, &NB};
        hipError_t le = hipLaunchCooperativeKernel(
            fused_kernel, dim3(s_grid), dim3(TPB), args, 0u, stream);
        s_mode = (le == hipSuccess) ? 1 : 2;
    }

    if (s_mode == 2) {
        // original 6-dispatch pipeline
        hipMemsetAsync(gCursor, 0, (size_t)NBMAX * 4, stream);
        mega_kernel<<<nbin + npre + nwcv, TPB, 0, stream>>>(
            src, dst, gCursor, tmp, feat, featb, W, Wb, E, N, nbin, npre);
        bucket_csr_kernel<<<NB, TPB, 0, stream>>>(tmp, gCursor, rsdeg, norm, csr, N);
        const int spmm_blocks = (N * 64 + TPB - 1) / TPB;
        spmm_kernel<<<spmm_blocks, TPB, 0, stream>>>(
            (const uint4*)featb, rsdeg, csr, norm, h1b, N);
        spmm_kernel<<<spmm_blocks, TPB, 0, stream>>>(
            (const uint4*)h1b, rsdeg, csr, norm, h2b, N);
    }

    const int ntiles = (N + 15) / 16;            // 6250
    gemm_mfma_kernel<<<GEMM_GRID, TPB, 0, stream>>>(
        (const ushort*)featb, (const ushort*)h1b, (const ushort*)h2b,
        Wb, bias, out, N, ntiles);
}

// Round 2
// 381.161 us; speedup vs baseline: 2.0314x; 2.0314x over previous
//
#include <hip/hip_runtime.h>
#include <hip/hip_bf16.h>

// TAGConv K=2, D=128. Round 9: revert to round-7 6-dispatch structure
// (307us known-good; the cooperative grid.sync cost ~190us/sync -> 774us)
// + spmm VALU cut: v_pk_fma_f32 (packed 2xFMA, VOP3P) replaces 8 scalar
// fmac with 4 packed ops per uint4; csr load made nontemporal so the
// 6.4MB stream stops evicting hot hin rows from L2.
// Pipeline: memset(1KB) -> mega -> bucket_csr -> spmm1 -> spmm2 -> gemm.

#define D 128
#define TPB 256
#define GEMM_GRID 768

#define BSH 9
#define BSZ 512              // nodes per bucket
#define NBMAX 256            // max buckets
#define EPT 16               // edges per thread in binscatter
#define CH (TPB * EPT)       // 4096 edges per WG
#define LCAP 16384           // fixed per-bucket region (avg fill ~8.2K, ~90 sigma)

typedef __attribute__((ext_vector_type(8))) short short8;
typedef __attribute__((ext_vector_type(4))) float f32x4;
typedef __attribute__((ext_vector_type(2))) float f32x2;

__device__ __forceinline__ ushort f2bf(float f) {
    unsigned u = __float_as_uint(f);
    u += 0x7fff + ((u >> 16) & 1);      // round-to-nearest-even
    return (ushort)(u >> 16);
}
__device__ __forceinline__ unsigned pack2bf(float x, float y) {
    return (unsigned)f2bf(x) | ((unsigned)f2bf(y) << 16);
}
__device__ __forceinline__ float bf_lo(unsigned v) { return __uint_as_float(v << 16); }
__device__ __forceinline__ float bf_hi(unsigned v) { return __uint_as_float(v & 0xffff0000u); }

// ---------------- mega: binscatter || prescale || wconv ----------------
// blocks [0, nbin): bin edges into fixed bucket regions (packed 4B:
//   pk = (src<<9)|(dst&511)); one global atomic per (WG,bucket).
// blocks [nbin, nbin+npre): featb = bf16(feat).
// blocks [nbin+npre, ...): Wb = bf16(W).
__global__ __launch_bounds__(TPB) void mega_kernel(
    const int* __restrict__ src, const int* __restrict__ dst,
    int* __restrict__ gCursor, unsigned* __restrict__ tmp,
    const float* __restrict__ feat, unsigned* __restrict__ featb,
    const float* __restrict__ W, ushort* __restrict__ Wb,
    int e, int n, int nbin, int npre) {
    __shared__ int hist[NBMAX];
    __shared__ int cellBase[NBMAX];
    int t = threadIdx.x;
    int bid = blockIdx.x;

    if (bid < nbin) {
        hist[t] = 0;
        __syncthreads();
        int base = bid * CH;
        int b[EPT]; unsigned pk[EPT]; int r[EPT];
#pragma unroll
        for (int k = 0; k < EPT; ++k) {
            int i = base + k * TPB + t;
            b[k] = -1;
            if (i < e) {
                int d = dst[i];
                b[k] = d >> BSH;
                pk[k] = ((unsigned)src[i] << BSH) | (unsigned)(d & (BSZ - 1));
                r[k] = atomicAdd(&hist[b[k]], 1);
            }
        }
        __syncthreads();
        int h = hist[t];
        cellBase[t] = h ? t * LCAP + atomicAdd(&gCursor[t], h) : 0;
        __syncthreads();
#pragma unroll
        for (int k = 0; k < EPT; ++k)
            if (b[k] >= 0) tmp[cellBase[b[k]] + r[k]] = pk[k];
    } else if (bid < nbin + npre) {
        int gid = (bid - nbin) * TPB + t;
        int node = gid >> 6, c = gid & 63;
        if (node >= n) return;
        float2 f = ((const float2*)(feat + (size_t)node * D))[c];
        featb[(size_t)node * 64 + c] = pack2bf(f.x, f.y);
    } else {
        int i = ((bid - nbin - npre) * TPB + t) * 4;   // D*384 = 49152 elems
        float4 w = *(const float4*)(W + i);
        ushort4 o;
        o.x = f2bf(w.x); o.y = f2bf(w.y); o.z = f2bf(w.z); o.w = f2bf(w.w);
        *(ushort4*)(Wb + i) = o;
    }
}

// ---------------- per-bucket CSR in LDS + sequential dump ----------
// One WG per bucket. Emits csr slice (coalesced, at bkt*LCAP), rsdeg, norm.
__global__ __launch_bounds__(TPB) void bucket_csr_kernel(
    const unsigned* __restrict__ tmp, const int* __restrict__ gCursor,
    int2* __restrict__ rsdeg, float* __restrict__ norm, int* __restrict__ csr,
    int n) {
    __shared__ int cnt[BSZ];
    __shared__ int off[BSZ];
    __shared__ int pr[TPB];
    __shared__ int lcsr[LCAP];
    int t = threadIdx.x;
    int bkt = blockIdx.x;
    int beg = bkt * LCAP;
    int m = gCursor[bkt];
    int end = beg + m;
    cnt[t] = 0; cnt[t + TPB] = 0;
    __syncthreads();
    for (int i = beg + t; i < end; i += TPB)
        atomicAdd(&cnt[tmp[i] & (BSZ - 1)], 1);
    __syncthreads();
    // exclusive scan of cnt[512] via 256-pair Hillis-Steele
    int c0 = cnt[2 * t], c1 = cnt[2 * t + 1];
    int own = c0 + c1;
    pr[t] = own;
    __syncthreads();
    for (int o = 1; o < TPB; o <<= 1) {
        int x = (t >= o) ? pr[t - o] : 0;
        __syncthreads();
        pr[t] += x;
        __syncthreads();
    }
    int ex = pr[t] - own;
    off[2 * t] = ex;
    off[2 * t + 1] = ex + c0;
    __syncthreads();
    cnt[t] = 0; cnt[t + TPB] = 0;          // reuse as rank counters
    __syncthreads();
    for (int i = beg + t; i < end; i += TPB) {
        unsigned v = tmp[i];
        int l = v & (BSZ - 1);
        int r = atomicAdd(&cnt[l], 1);
        int idx = off[l] + r;
        if (idx < LCAP) lcsr[idx] = (int)(v >> BSH);
    }
    __syncthreads();
    int mm = m < LCAP ? m : LCAP;
    for (int i = t; i < mm; i += TPB) csr[beg + i] = lcsr[i];   // sequential
    int node0 = bkt << BSH;
    for (int l = t; l < BSZ; l += TPB) {
        int node = node0 + l;
        if (node < n) {
            rsdeg[node] = make_int2(beg + off[l], cnt[l]);
            norm[node] = rsqrtf((float)cnt[l]);
        }
    }
}

// ---------------- SpMM: hout[v] = bf16( norm[v] * sum_u norm[u]*hin[u] ) ----
// One wave per dst node; quarter-wave q handles edge beg+j*4+q; c = lane&15
// handles a 16B column chunk. 1 KB per gather instruction; unroll 4.
// Round 9: accumulate via v_pk_fma_f32 (2 FMA/inst) -> 4 packed fma per
// uint4 instead of 8 scalar; csr stream load nontemporal (keeps hin in L2).
__global__ __launch_bounds__(TPB) void spmm_kernel(
    const uint4* __restrict__ hin4, const int2* __restrict__ rsdeg,
    const int* __restrict__ csr, const float* __restrict__ norm,
    unsigned* __restrict__ hout, int n) {
    int w = (blockIdx.x * TPB + threadIdx.x) >> 6;
    if (w >= n) return;
    int lane = threadIdx.x & 63;
    int q = lane >> 4;
    int c = lane & 15;
    int2 rd = rsdeg[w];
    int beg = rd.x, end = rd.x + rd.y;
    f32x2 a0 = {}, a1 = {}, a2 = {}, a3 = {};
#pragma unroll 4
    for (int j = beg + q; j < end; j += 4) {
        int u = __builtin_nontemporal_load(&csr[j]);
        float s = norm[u];
        f32x2 ss = {s, s};
        uint4 v = hin4[(u << 4) + c];
        f32x2 h0 = {bf_lo(v.x), bf_hi(v.x)};
        f32x2 h1 = {bf_lo(v.y), bf_hi(v.y)};
        f32x2 h2 = {bf_lo(v.z), bf_hi(v.z)};
        f32x2 h3 = {bf_lo(v.w), bf_hi(v.w)};
        asm("v_pk_fma_f32 %0, %1, %2, %0" : "+v"(a0) : "v"(ss), "v"(h0));
        asm("v_pk_fma_f32 %0, %1, %2, %0" : "+v"(a1) : "v"(ss), "v"(h1));
        asm("v_pk_fma_f32 %0, %1, %2, %0" : "+v"(a2) : "v"(ss), "v"(h2));
        asm("v_pk_fma_f32 %0, %1, %2, %0" : "+v"(a3) : "v"(ss), "v"(h3));
    }
    float acc[8];
    acc[0] = a0[0]; acc[1] = a0[1];
    acc[2] = a1[0]; acc[3] = a1[1];
    acc[4] = a2[0]; acc[5] = a2[1];
    acc[6] = a3[0]; acc[7] = a3[1];
#pragma unroll
    for (int k = 0; k < 8; ++k) {
        acc[k] += __shfl_xor(acc[k], 16, 64);
        acc[k] += __shfl_xor(acc[k], 32, 64);
    }
    if (q == 0) {
        float nv = norm[w];
        uint4 r;
        r.x = pack2bf(acc[0] * nv, acc[1] * nv);
        r.y = pack2bf(acc[2] * nv, acc[3] * nv);
        r.z = pack2bf(acc[4] * nv, acc[5] * nv);
        r.w = pack2bf(acc[6] * nv, acc[7] * nv);
        *(uint4*)(hout + (size_t)w * 64 + c * 4) = r;
    }
}

// ---------------- GEMM: out[n][128] = [featb|h1b|h2b] @ Wb^T + b ----------------
// 4 waves/block; wave owns a 32-col W slice in registers (24 bf16 frags).
// A frag: row m=lane&15, k=(lane>>4)*8+j.  C/D: col=lane&15, row=(lane>>4)*4+reg.
__global__ __launch_bounds__(TPB) void gemm_mfma_kernel(
    const ushort* __restrict__ featb, const ushort* __restrict__ h1b,
    const ushort* __restrict__ h2b, const ushort* __restrict__ Wb,
    const float* __restrict__ bias, float* __restrict__ out, int n, int ntiles) {
    int lane = threadIdx.x & 63;
    int wave = threadIdx.x >> 6;
    int m = lane & 15, q = lane >> 4;

    short8 b[12][2];
#pragma unroll
    for (int ks = 0; ks < 12; ++ks)
#pragma unroll
        for (int t = 0; t < 2; ++t)
            b[ks][t] = *(const short8*)(Wb + (size_t)(wave * 32 + t * 16 + m) * 384
                                        + ks * 32 + q * 8);
    float bv0 = bias[wave * 32 + m];
    float bv1 = bias[wave * 32 + 16 + m];

    const ushort* srcs[3] = {featb, h1b, h2b};

    for (int tile = blockIdx.x; tile < ntiles; tile += gridDim.x) {
        int row = tile * 16 + m;
        bool va = row < n;
        size_t arow = (size_t)row * D;
        short8 a[12] = {};
        if (va) {
#pragma unroll
            for (int ks = 0; ks < 12; ++ks)
                a[ks] = *(const short8*)(srcs[ks >> 2] + arow + (ks & 3) * 32 + q * 8);
        }
        f32x4 acc0 = {}, acc1 = {};
#pragma unroll
        for (int ks = 0; ks < 12; ++ks) {
            acc0 = __builtin_amdgcn_mfma_f32_16x16x32_bf16(a[ks], b[ks][0], acc0, 0, 0, 0);
            acc1 = __builtin_amdgcn_mfma_f32_16x16x32_bf16(a[ks], b[ks][1], acc1, 0, 0, 0);
        }
        int r0 = tile * 16 + q * 4;
#pragma unroll
        for (int r = 0; r < 4; ++r) {
            int rw = r0 + r;
            if (rw < n) {
                size_t o = (size_t)rw * D + wave * 32 + m;
                out[o] = acc0[r] + bv0;
                out[o + 16] = acc1[r] + bv1;
            }
        }
    }
}

extern "C" void kernel_launch(void* const* d_in, const int* in_sizes, int n_in,
                              void* d_out, int out_size, void* d_ws, size_t ws_size,
                              hipStream_t stream) {
    const float* feat = (const float*)d_in[0];
    const int* src    = (const int*)d_in[1];
    const int* dst    = (const int*)d_in[2];
    const float* W    = (const float*)d_in[3];
    const float* bias = (const float*)d_in[4];
    float* out        = (float*)d_out;

    const int N = in_sizes[0] / D;        // 100000
    const int E = in_sizes[1];            // 1600000
    const int NB = (N + BSZ - 1) >> BSH;  // 196

    char* ws = (char*)d_ws;
    size_t off = 0;
    auto bump = [&](size_t bytes) {
        char* p = ws + off;
        off += (bytes + 255) & ~(size_t)255;
        return p;
    };
    int* gCursor     = (int*)bump((size_t)NBMAX * 4);            // memset to 0
    float* norm      = (float*)bump((size_t)N * 4);
    int2* rsdeg      = (int2*)bump((size_t)N * 8);
    unsigned* tmp    = (unsigned*)bump((size_t)NB * LCAP * 4);   // 12.85 MB
    int* csr         = (int*)bump((size_t)NB * LCAP * 4);        // 12.85 MB
    unsigned* featb  = (unsigned*)bump((size_t)N * 64 * 4);      // bf16x2 rows
    unsigned* h1b    = (unsigned*)bump((size_t)N * 64 * 4);
    unsigned* h2b    = (unsigned*)bump((size_t)N * 64 * 4);
    ushort* Wb       = (ushort*)bump((size_t)D * 384 * 2);
    (void)ws_size;

    hipMemsetAsync(gCursor, 0, (size_t)NBMAX * 4, stream);

    const int nbin = (E + CH - 1) / CH;                // 391
    const int npre = (N * 64 + TPB - 1) / TPB;         // 25000
    const int nwcv = (D * 384 / 4 + TPB - 1) / TPB;    // 48
    mega_kernel<<<nbin + npre + nwcv, TPB, 0, stream>>>(
        src, dst, gCursor, tmp, feat, featb, W, Wb, E, N, nbin, npre);

    bucket_csr_kernel<<<NB, TPB, 0, stream>>>(tmp, gCursor, rsdeg, norm, csr, N);

    const int spmm_blocks = (N * 64 + TPB - 1) / TPB;  // 1 wave per node
    spmm_kernel<<<spmm_blocks, TPB, 0, stream>>>((const uint4*)featb, rsdeg, csr, norm, h1b, N);
    spmm_kernel<<<spmm_blocks, TPB, 0, stream>>>((const uint4*)h1b, rsdeg, csr, norm, h2b, N);

    const int ntiles = (N + 15) / 16;                  // 6250
    gemm_mfma_kernel<<<GEMM_GRID, TPB, 0, stream>>>(
        (const ushort*)featb, (const ushort*)h1b, (const ushort*)h2b,
        Wb, bias, out, N, ntiles);
}

// Round 3
// 316.905 us; speedup vs baseline: 2.4433x; 1.2028x over previous
//
#include <hip/hip_runtime.h>
#include <hip/hip_bf16.h>

// TAGConv K=2, D=128. Round 10.
// Round-9 lesson: packed-asm spmm collapsed VGPR 32->16, killed load
// pipelining (62.5 -> 99us). Revert to scalar fmaf. New theory: with avg
// deg 16 (4 trips/quarter-wave), ~37% of edges run in the serial unroll
// remainder at full dependent-load latency. Fix: manual 2-deep software
// pipeline (prefetch next edge's csr/norm/row before consuming current),
// effective at every trip count. Also bucket_csr TPB 256->512 (1 block/CU,
// serial-pass bound; scan becomes 512-thread Hillis-Steele, TPB==BSZ).
// Pipeline: memset(1KB) -> mega -> bucket_csr -> spmm1 -> spmm2 -> gemm.

#define D 128
#define TPB 256
#define CSR_TPB 512
#define GEMM_GRID 768

#define BSH 9
#define BSZ 512              // nodes per bucket
#define NBMAX 256            // max buckets
#define EPT 16               // edges per thread in binscatter
#define CH (TPB * EPT)       // 4096 edges per WG
#define LCAP 16384           // fixed per-bucket region (avg fill ~8.2K, ~90 sigma)

typedef __attribute__((ext_vector_type(8))) short short8;
typedef __attribute__((ext_vector_type(4))) float f32x4;

__device__ __forceinline__ ushort f2bf(float f) {
    unsigned u = __float_as_uint(f);
    u += 0x7fff + ((u >> 16) & 1);      // round-to-nearest-even
    return (ushort)(u >> 16);
}
__device__ __forceinline__ unsigned pack2bf(float x, float y) {
    return (unsigned)f2bf(x) | ((unsigned)f2bf(y) << 16);
}
__device__ __forceinline__ float bf_lo(unsigned v) { return __uint_as_float(v << 16); }
__device__ __forceinline__ float bf_hi(unsigned v) { return __uint_as_float(v & 0xffff0000u); }

// ---------------- mega: binscatter || prescale || wconv ----------------
// blocks [0, nbin): bin edges into fixed bucket regions (packed 4B:
//   pk = (src<<9)|(dst&511)); one global atomic per (WG,bucket).
// blocks [nbin, nbin+npre): featb = bf16(feat).
// blocks [nbin+npre, ...): Wb = bf16(W).
__global__ __launch_bounds__(TPB) void mega_kernel(
    const int* __restrict__ src, const int* __restrict__ dst,
    int* __restrict__ gCursor, unsigned* __restrict__ tmp,
    const float* __restrict__ feat, unsigned* __restrict__ featb,
    const float* __restrict__ W, ushort* __restrict__ Wb,
    int e, int n, int nbin, int npre) {
    __shared__ int hist[NBMAX];
    __shared__ int cellBase[NBMAX];
    int t = threadIdx.x;
    int bid = blockIdx.x;

    if (bid < nbin) {
        hist[t] = 0;
        __syncthreads();
        int base = bid * CH;
        int b[EPT]; unsigned pk[EPT]; int r[EPT];
#pragma unroll
        for (int k = 0; k < EPT; ++k) {
            int i = base + k * TPB + t;
            b[k] = -1;
            if (i < e) {
                int d = dst[i];
                b[k] = d >> BSH;
                pk[k] = ((unsigned)src[i] << BSH) | (unsigned)(d & (BSZ - 1));
                r[k] = atomicAdd(&hist[b[k]], 1);
            }
        }
        __syncthreads();
        int h = hist[t];
        cellBase[t] = h ? t * LCAP + atomicAdd(&gCursor[t], h) : 0;
        __syncthreads();
#pragma unroll
        for (int k = 0; k < EPT; ++k)
            if (b[k] >= 0) tmp[cellBase[b[k]] + r[k]] = pk[k];
    } else if (bid < nbin + npre) {
        int gid = (bid - nbin) * TPB + t;
        int node = gid >> 6, c = gid & 63;
        if (node >= n) return;
        float2 f = ((const float2*)(feat + (size_t)node * D))[c];
        featb[(size_t)node * 64 + c] = pack2bf(f.x, f.y);
    } else {
        int i = ((bid - nbin - npre) * TPB + t) * 4;   // D*384 = 49152 elems
        float4 w = *(const float4*)(W + i);
        ushort4 o;
        o.x = f2bf(w.x); o.y = f2bf(w.y); o.z = f2bf(w.z); o.w = f2bf(w.w);
        *(ushort4*)(Wb + i) = o;
    }
}

// ---------------- per-bucket CSR in LDS + sequential dump ----------
// One WG per bucket, CSR_TPB=512 threads (== BSZ). Emits csr slice
// (coalesced, at bkt*LCAP), rsdeg, norm.
__global__ __launch_bounds__(CSR_TPB) void bucket_csr_kernel(
    const unsigned* __restrict__ tmp, const int* __restrict__ gCursor,
    int2* __restrict__ rsdeg, float* __restrict__ norm, int* __restrict__ csr,
    int n) {
    __shared__ int cnt[BSZ];
    __shared__ int off[BSZ];
    __shared__ int pr[BSZ];
    __shared__ int lcsr[LCAP];
    int t = threadIdx.x;
    int bkt = blockIdx.x;
    int beg = bkt * LCAP;
    int m = gCursor[bkt];
    int end = beg + m;
    cnt[t] = 0;
    __syncthreads();
    for (int i = beg + t; i < end; i += CSR_TPB)
        atomicAdd(&cnt[tmp[i] & (BSZ - 1)], 1);
    __syncthreads();
    // exclusive scan of cnt[512] via 512-thread Hillis-Steele
    int own = cnt[t];
    pr[t] = own;
    __syncthreads();
    for (int o = 1; o < BSZ; o <<= 1) {
        int x = (t >= o) ? pr[t - o] : 0;
        __syncthreads();
        pr[t] += x;
        __syncthreads();
    }
    off[t] = pr[t] - own;
    __syncthreads();
    cnt[t] = 0;                            // reuse as rank counters
    __syncthreads();
    for (int i = beg + t; i < end; i += CSR_TPB) {
        unsigned v = tmp[i];
        int l = v & (BSZ - 1);
        int r = atomicAdd(&cnt[l], 1);
        int idx = off[l] + r;
        if (idx < LCAP) lcsr[idx] = (int)(v >> BSH);
    }
    __syncthreads();
    int mm = m < LCAP ? m : LCAP;
    for (int i = t; i < mm; i += CSR_TPB) csr[beg + i] = lcsr[i];   // sequential
    int node0 = bkt << BSH;
    {
        int node = node0 + t;
        if (node < n) {
            rsdeg[node] = make_int2(beg + off[t], cnt[t]);
            norm[node] = rsqrtf((float)cnt[t]);
        }
    }
}

// ---------------- SpMM: hout[v] = bf16( norm[v] * sum_u norm[u]*hin[u] ) ----
// One wave per dst node; quarter-wave q handles edge beg+j*4+q; c = lane&15
// handles a 16B column chunk. 1 KB per gather instruction.
// Round 10: manual 2-deep software pipeline -- issue edge j+4's csr/norm/row
// loads before consuming edge j's row, so pipelining holds at every degree
// (the old "#pragma unroll 4" left ~37% of edges in a serial remainder).
__global__ __launch_bounds__(TPB) void spmm_kernel(
    const uint4* __restrict__ hin4, const int2* __restrict__ rsdeg,
    const int* __restrict__ csr, const float* __restrict__ norm,
    unsigned* __restrict__ hout, int n) {
    int w = (blockIdx.x * TPB + threadIdx.x) >> 6;
    if (w >= n) return;
    int lane = threadIdx.x & 63;
    int q = lane >> 4;
    int c = lane & 15;
    int2 rd = rsdeg[w];
    int beg = rd.x, end = rd.x + rd.y;
    float acc[8] = {};
    int j = beg + q;
    if (j < end) {
        int u = csr[j];
        float s = norm[u];
        uint4 v = hin4[(u << 4) + c];
        for (j += 4; j < end; j += 4) {
            int u2 = csr[j];                     // prefetch next edge
            float s2 = norm[u2];
            uint4 v2 = hin4[(u2 << 4) + c];
            acc[0] = fmaf(s, bf_lo(v.x), acc[0]);   // consume current
            acc[1] = fmaf(s, bf_hi(v.x), acc[1]);
            acc[2] = fmaf(s, bf_lo(v.y), acc[2]);
            acc[3] = fmaf(s, bf_hi(v.y), acc[3]);
            acc[4] = fmaf(s, bf_lo(v.z), acc[4]);
            acc[5] = fmaf(s, bf_hi(v.z), acc[5]);
            acc[6] = fmaf(s, bf_lo(v.w), acc[6]);
            acc[7] = fmaf(s, bf_hi(v.w), acc[7]);
            s = s2; v = v2;
        }
        acc[0] = fmaf(s, bf_lo(v.x), acc[0]);
        acc[1] = fmaf(s, bf_hi(v.x), acc[1]);
        acc[2] = fmaf(s, bf_lo(v.y), acc[2]);
        acc[3] = fmaf(s, bf_hi(v.y), acc[3]);
        acc[4] = fmaf(s, bf_lo(v.z), acc[4]);
        acc[5] = fmaf(s, bf_hi(v.z), acc[5]);
        acc[6] = fmaf(s, bf_lo(v.w), acc[6]);
        acc[7] = fmaf(s, bf_hi(v.w), acc[7]);
    }
#pragma unroll
    for (int k = 0; k < 8; ++k) {
        acc[k] += __shfl_xor(acc[k], 16, 64);
        acc[k] += __shfl_xor(acc[k], 32, 64);
    }
    if (q == 0) {
        float nv = norm[w];
        uint4 r;
        r.x = pack2bf(acc[0] * nv, acc[1] * nv);
        r.y = pack2bf(acc[2] * nv, acc[3] * nv);
        r.z = pack2bf(acc[4] * nv, acc[5] * nv);
        r.w = pack2bf(acc[6] * nv, acc[7] * nv);
        *(uint4*)(hout + (size_t)w * 64 + c * 4) = r;
    }
}

// ---------------- GEMM: out[n][128] = [featb|h1b|h2b] @ Wb^T + b ----------------
// 4 waves/block; wave owns a 32-col W slice in registers (24 bf16 frags).
// A frag: row m=lane&15, k=(lane>>4)*8+j.  C/D: col=lane&15, row=(lane>>4)*4+reg.
__global__ __launch_bounds__(TPB) void gemm_mfma_kernel(
    const ushort* __restrict__ featb, const ushort* __restrict__ h1b,
    const ushort* __restrict__ h2b, const ushort* __restrict__ Wb,
    const float* __restrict__ bias, float* __restrict__ out, int n, int ntiles) {
    int lane = threadIdx.x & 63;
    int wave = threadIdx.x >> 6;
    int m = lane & 15, q = lane >> 4;

    short8 b[12][2];
#pragma unroll
    for (int ks = 0; ks < 12; ++ks)
#pragma unroll
        for (int t = 0; t < 2; ++t)
            b[ks][t] = *(const short8*)(Wb + (size_t)(wave * 32 + t * 16 + m) * 384
                                        + ks * 32 + q * 8);
    float bv0 = bias[wave * 32 + m];
    float bv1 = bias[wave * 32 + 16 + m];

    const ushort* srcs[3] = {featb, h1b, h2b};

    for (int tile = blockIdx.x; tile < ntiles; tile += gridDim.x) {
        int row = tile * 16 + m;
        bool va = row < n;
        size_t arow = (size_t)row * D;
        short8 a[12] = {};
        if (va) {
#pragma unroll
            for (int ks = 0; ks < 12; ++ks)
                a[ks] = *(const short8*)(srcs[ks >> 2] + arow + (ks & 3) * 32 + q * 8);
        }
        f32x4 acc0 = {}, acc1 = {};
#pragma unroll
        for (int ks = 0; ks < 12; ++ks) {
            acc0 = __builtin_amdgcn_mfma_f32_16x16x32_bf16(a[ks], b[ks][0], acc0, 0, 0, 0);
            acc1 = __builtin_amdgcn_mfma_f32_16x16x32_bf16(a[ks], b[ks][1], acc1, 0, 0, 0);
        }
        int r0 = tile * 16 + q * 4;
#pragma unroll
        for (int r = 0; r < 4; ++r) {
            int rw = r0 + r;
            if (rw < n) {
                size_t o = (size_t)rw * D + wave * 32 + m;
                out[o] = acc0[r] + bv0;
                out[o + 16] = acc1[r] + bv1;
            }
        }
    }
}

extern "C" void kernel_launch(void* const* d_in, const int* in_sizes, int n_in,
                              void* d_out, int out_size, void* d_ws, size_t ws_size,
                              hipStream_t stream) {
    const float* feat = (const float*)d_in[0];
    const int* src    = (const int*)d_in[1];
    const int* dst    = (const int*)d_in[2];
    const float* W    = (const float*)d_in[3];
    const float* bias = (const float*)d_in[4];
    float* out        = (float*)d_out;

    const int N = in_sizes[0] / D;        // 100000
    const int E = in_sizes[1];            // 1600000
    const int NB = (N + BSZ - 1) >> BSH;  // 196

    char* ws = (char*)d_ws;
    size_t off = 0;
    auto bump = [&](size_t bytes) {
        char* p = ws + off;
        off += (bytes + 255) & ~(size_t)255;
        return p;
    };
    int* gCursor     = (int*)bump((size_t)NBMAX * 4);            // memset to 0
    float* norm      = (float*)bump((size_t)N * 4);
    int2* rsdeg      = (int2*)bump((size_t)N * 8);
    unsigned* tmp    = (unsigned*)bump((size_t)NB * LCAP * 4);   // 12.85 MB
    int* csr         = (int*)bump((size_t)NB * LCAP * 4);        // 12.85 MB
    unsigned* featb  = (unsigned*)bump((size_t)N * 64 * 4);      // bf16x2 rows
    unsigned* h1b    = (unsigned*)bump((size_t)N * 64 * 4);
    unsigned* h2b    = (unsigned*)bump((size_t)N * 64 * 4);
    ushort* Wb       = (ushort*)bump((size_t)D * 384 * 2);
    (void)ws_size;

    hipMemsetAsync(gCursor, 0, (size_t)NBMAX * 4, stream);

    const int nbin = (E + CH - 1) / CH;                // 391
    const int npre = (N * 64 + TPB - 1) / TPB;         // 25000
    const int nwcv = (D * 384 / 4 + TPB - 1) / TPB;    // 48
    mega_kernel<<<nbin + npre + nwcv, TPB, 0, stream>>>(
        src, dst, gCursor, tmp, feat, featb, W, Wb, E, N, nbin, npre);

    bucket_csr_kernel<<<NB, CSR_TPB, 0, stream>>>(tmp, gCursor, rsdeg, norm, csr, N);

    const int spmm_blocks = (N * 64 + TPB - 1) / TPB;  // 1 wave per node
    spmm_kernel<<<spmm_blocks, TPB, 0, stream>>>((const uint4*)featb, rsdeg, csr, norm, h1b, N);
    spmm_kernel<<<spmm_blocks, TPB, 0, stream>>>((const uint4*)h1b, rsdeg, csr, norm, h2b, N);

    const int ntiles = (N + 15) / 16;                  // 6250
    gemm_mfma_kernel<<<GEMM_GRID, TPB, 0, stream>>>(
        (const ushort*)featb, (const ushort*)h1b, (const ushort*)h2b,
        Wb, bias, out, N, ntiles);
}

// Round 4
// 301.377 us; speedup vs baseline: 2.5692x; 1.0515x over previous
//
#include <hip/hip_runtime.h>
#include <hip/hip_bf16.h>

// TAGConv K=2, D=128. Round 11.
// Rounds 9/10 lesson: any hand-restructure of the spmm loop makes the
// scheduler re-serialize at VGPR=16 (worse). Round-0 unroll-4 body at
// VGPR=32 is the best codegen but fits only ~2 row-gathers in flight.
// gfx950 VGPR pool: <=64 VGPR keeps full 8 waves/SIMD, so doubling the
// budget is free. Fix: exact round-0 spmm body + __launch_bounds__(256,8)
// (pins 8 waves/EU -> 64-VGPR cap, compiler may pipeline all 4 gathers).
// Keep round-10's 512-thread bucket_csr (~5us). Everything else round-0.
// Pipeline: memset(1KB) -> mega -> bucket_csr -> spmm1 -> spmm2 -> gemm.

#define D 128
#define TPB 256
#define CSR_TPB 512
#define GEMM_GRID 768

#define BSH 9
#define BSZ 512              // nodes per bucket
#define NBMAX 256            // max buckets
#define EPT 16               // edges per thread in binscatter
#define CH (TPB * EPT)       // 4096 edges per WG
#define LCAP 16384           // fixed per-bucket region (avg fill ~8.2K, ~90 sigma)

typedef __attribute__((ext_vector_type(8))) short short8;
typedef __attribute__((ext_vector_type(4))) float f32x4;

__device__ __forceinline__ ushort f2bf(float f) {
    unsigned u = __float_as_uint(f);
    u += 0x7fff + ((u >> 16) & 1);      // round-to-nearest-even
    return (ushort)(u >> 16);
}
__device__ __forceinline__ unsigned pack2bf(float x, float y) {
    return (unsigned)f2bf(x) | ((unsigned)f2bf(y) << 16);
}
__device__ __forceinline__ float bf_lo(unsigned v) { return __uint_as_float(v << 16); }
__device__ __forceinline__ float bf_hi(unsigned v) { return __uint_as_float(v & 0xffff0000u); }

// ---------------- mega: binscatter || prescale || wconv ----------------
// blocks [0, nbin): bin edges into fixed bucket regions (packed 4B:
//   pk = (src<<9)|(dst&511)); one global atomic per (WG,bucket).
// blocks [nbin, nbin+npre): featb = bf16(feat).
// blocks [nbin+npre, ...): Wb = bf16(W).
__global__ __launch_bounds__(TPB) void mega_kernel(
    const int* __restrict__ src, const int* __restrict__ dst,
    int* __restrict__ gCursor, unsigned* __restrict__ tmp,
    const float* __restrict__ feat, unsigned* __restrict__ featb,
    const float* __restrict__ W, ushort* __restrict__ Wb,
    int e, int n, int nbin, int npre) {
    __shared__ int hist[NBMAX];
    __shared__ int cellBase[NBMAX];
    int t = threadIdx.x;
    int bid = blockIdx.x;

    if (bid < nbin) {
        hist[t] = 0;
        __syncthreads();
        int base = bid * CH;
        int b[EPT]; unsigned pk[EPT]; int r[EPT];
#pragma unroll
        for (int k = 0; k < EPT; ++k) {
            int i = base + k * TPB + t;
            b[k] = -1;
            if (i < e) {
                int d = dst[i];
                b[k] = d >> BSH;
                pk[k] = ((unsigned)src[i] << BSH) | (unsigned)(d & (BSZ - 1));
                r[k] = atomicAdd(&hist[b[k]], 1);
            }
        }
        __syncthreads();
        int h = hist[t];
        cellBase[t] = h ? t * LCAP + atomicAdd(&gCursor[t], h) : 0;
        __syncthreads();
#pragma unroll
        for (int k = 0; k < EPT; ++k)
            if (b[k] >= 0) tmp[cellBase[b[k]] + r[k]] = pk[k];
    } else if (bid < nbin + npre) {
        int gid = (bid - nbin) * TPB + t;
        int node = gid >> 6, c = gid & 63;
        if (node >= n) return;
        float2 f = ((const float2*)(feat + (size_t)node * D))[c];
        featb[(size_t)node * 64 + c] = pack2bf(f.x, f.y);
    } else {
        int i = ((bid - nbin - npre) * TPB + t) * 4;   // D*384 = 49152 elems
        float4 w = *(const float4*)(W + i);
        ushort4 o;
        o.x = f2bf(w.x); o.y = f2bf(w.y); o.z = f2bf(w.z); o.w = f2bf(w.w);
        *(ushort4*)(Wb + i) = o;
    }
}

// ---------------- per-bucket CSR in LDS + sequential dump ----------
// One WG per bucket, CSR_TPB=512 threads (== BSZ). Emits csr slice
// (coalesced, at bkt*LCAP), rsdeg, norm.
__global__ __launch_bounds__(CSR_TPB) void bucket_csr_kernel(
    const unsigned* __restrict__ tmp, const int* __restrict__ gCursor,
    int2* __restrict__ rsdeg, float* __restrict__ norm, int* __restrict__ csr,
    int n) {
    __shared__ int cnt[BSZ];
    __shared__ int off[BSZ];
    __shared__ int pr[BSZ];
    __shared__ int lcsr[LCAP];
    int t = threadIdx.x;
    int bkt = blockIdx.x;
    int beg = bkt * LCAP;
    int m = gCursor[bkt];
    int end = beg + m;
    cnt[t] = 0;
    __syncthreads();
    for (int i = beg + t; i < end; i += CSR_TPB)
        atomicAdd(&cnt[tmp[i] & (BSZ - 1)], 1);
    __syncthreads();
    // exclusive scan of cnt[512] via 512-thread Hillis-Steele
    int own = cnt[t];
    pr[t] = own;
    __syncthreads();
    for (int o = 1; o < BSZ; o <<= 1) {
        int x = (t >= o) ? pr[t - o] : 0;
        __syncthreads();
        pr[t] += x;
        __syncthreads();
    }
    off[t] = pr[t] - own;
    __syncthreads();
    cnt[t] = 0;                            // reuse as rank counters
    __syncthreads();
    for (int i = beg + t; i < end; i += CSR_TPB) {
        unsigned v = tmp[i];
        int l = v & (BSZ - 1);
        int r = atomicAdd(&cnt[l], 1);
        int idx = off[l] + r;
        if (idx < LCAP) lcsr[idx] = (int)(v >> BSH);
    }
    __syncthreads();
    int mm = m < LCAP ? m : LCAP;
    for (int i = t; i < mm; i += CSR_TPB) csr[beg + i] = lcsr[i];   // sequential
    int node0 = bkt << BSH;
    {
        int node = node0 + t;
        if (node < n) {
            rsdeg[node] = make_int2(beg + off[t], cnt[t]);
            norm[node] = rsqrtf((float)cnt[t]);
        }
    }
}

// ---------------- SpMM: hout[v] = bf16( norm[v] * sum_u norm[u]*hin[u] ) ----
// One wave per dst node; quarter-wave q handles edge beg+j*4+q; c = lane&15
// handles a 16B column chunk. 1 KB per gather instruction; unroll 4.
// Round 11: exact round-0 body; __launch_bounds__(TPB,8) raises the VGPR
// budget 32->64 at zero occupancy cost so the scheduler can keep all 4
// unrolled row-gathers in flight (round-0's 32-VGPR heuristic fit ~2).
__global__ __launch_bounds__(TPB, 8) void spmm_kernel(
    const uint4* __restrict__ hin4, const int2* __restrict__ rsdeg,
    const int* __restrict__ csr, const float* __restrict__ norm,
    unsigned* __restrict__ hout, int n) {
    int w = (blockIdx.x * TPB + threadIdx.x) >> 6;
    if (w >= n) return;
    int lane = threadIdx.x & 63;
    int q = lane >> 4;
    int c = lane & 15;
    int2 rd = rsdeg[w];
    int beg = rd.x, end = rd.x + rd.y;
    float acc[8] = {};
#pragma unroll 4
    for (int j = beg + q; j < end; j += 4) {
        int u = csr[j];
        float s = norm[u];
        uint4 v = hin4[(u << 4) + c];
        acc[0] = fmaf(s, bf_lo(v.x), acc[0]);
        acc[1] = fmaf(s, bf_hi(v.x), acc[1]);
        acc[2] = fmaf(s, bf_lo(v.y), acc[2]);
        acc[3] = fmaf(s, bf_hi(v.y), acc[3]);
        acc[4] = fmaf(s, bf_lo(v.z), acc[4]);
        acc[5] = fmaf(s, bf_hi(v.z), acc[5]);
        acc[6] = fmaf(s, bf_lo(v.w), acc[6]);
        acc[7] = fmaf(s, bf_hi(v.w), acc[7]);
    }
#pragma unroll
    for (int k = 0; k < 8; ++k) {
        acc[k] += __shfl_xor(acc[k], 16, 64);
        acc[k] += __shfl_xor(acc[k], 32, 64);
    }
    if (q == 0) {
        float nv = norm[w];
        uint4 r;
        r.x = pack2bf(acc[0] * nv, acc[1] * nv);
        r.y = pack2bf(acc[2] * nv, acc[3] * nv);
        r.z = pack2bf(acc[4] * nv, acc[5] * nv);
        r.w = pack2bf(acc[6] * nv, acc[7] * nv);
        *(uint4*)(hout + (size_t)w * 64 + c * 4) = r;
    }
}

// ---------------- GEMM: out[n][128] = [featb|h1b|h2b] @ Wb^T + b ----------------
// 4 waves/block; wave owns a 32-col W slice in registers (24 bf16 frags).
// A frag: row m=lane&15, k=(lane>>4)*8+j.  C/D: col=lane&15, row=(lane>>4)*4+reg.
__global__ __launch_bounds__(TPB) void gemm_mfma_kernel(
    const ushort* __restrict__ featb, const ushort* __restrict__ h1b,
    const ushort* __restrict__ h2b, const ushort* __restrict__ Wb,
    const float* __restrict__ bias, float* __restrict__ out, int n, int ntiles) {
    int lane = threadIdx.x & 63;
    int wave = threadIdx.x >> 6;
    int m = lane & 15, q = lane >> 4;

    short8 b[12][2];
#pragma unroll
    for (int ks = 0; ks < 12; ++ks)
#pragma unroll
        for (int t = 0; t < 2; ++t)
            b[ks][t] = *(const short8*)(Wb + (size_t)(wave * 32 + t * 16 + m) * 384
                                        + ks * 32 + q * 8);
    float bv0 = bias[wave * 32 + m];
    float bv1 = bias[wave * 32 + 16 + m];

    const ushort* srcs[3] = {featb, h1b, h2b};

    for (int tile = blockIdx.x; tile < ntiles; tile += gridDim.x) {
        int row = tile * 16 + m;
        bool va = row < n;
        size_t arow = (size_t)row * D;
        short8 a[12] = {};
        if (va) {
#pragma unroll
            for (int ks = 0; ks < 12; ++ks)
                a[ks] = *(const short8*)(srcs[ks >> 2] + arow + (ks & 3) * 32 + q * 8);
        }
        f32x4 acc0 = {}, acc1 = {};
#pragma unroll
        for (int ks = 0; ks < 12; ++ks) {
            acc0 = __builtin_amdgcn_mfma_f32_16x16x32_bf16(a[ks], b[ks][0], acc0, 0, 0, 0);
            acc1 = __builtin_amdgcn_mfma_f32_16x16x32_bf16(a[ks], b[ks][1], acc1, 0, 0, 0);
        }
        int r0 = tile * 16 + q * 4;
#pragma unroll
        for (int r = 0; r < 4; ++r) {
            int rw = r0 + r;
            if (rw < n) {
                size_t o = (size_t)rw * D + wave * 32 + m;
                out[o] = acc0[r] + bv0;
                out[o + 16] = acc1[r] + bv1;
            }
        }
    }
}

extern "C" void kernel_launch(void* const* d_in, const int* in_sizes, int n_in,
                              void* d_out, int out_size, void* d_ws, size_t ws_size,
                              hipStream_t stream) {
    const float* feat = (const float*)d_in[0];
    const int* src    = (const int*)d_in[1];
    const int* dst    = (const int*)d_in[2];
    const float* W    = (const float*)d_in[3];
    const float* bias = (const float*)d_in[4];
    float* out        = (float*)d_out;

    const int N = in_sizes[0] / D;        // 100000
    const int E = in_sizes[1];            // 1600000
    const int NB = (N + BSZ - 1) >> BSH;  // 196

    char* ws = (char*)d_ws;
    size_t off = 0;
    auto bump = [&](size_t bytes) {
        char* p = ws + off;
        off += (bytes + 255) & ~(size_t)255;
        return p;
    };
    int* gCursor     = (int*)bump((size_t)NBMAX * 4);            // memset to 0
    float* norm      = (float*)bump((size_t)N * 4);
    int2* rsdeg      = (int2*)bump((size_t)N * 8);
    unsigned* tmp    = (unsigned*)bump((size_t)NB * LCAP * 4);   // 12.85 MB
    int* csr         = (int*)bump((size_t)NB * LCAP * 4);        // 12.85 MB
    unsigned* featb  = (unsigned*)bump((size_t)N * 64 * 4);      // bf16x2 rows
    unsigned* h1b    = (unsigned*)bump((size_t)N * 64 * 4);
    unsigned* h2b    = (unsigned*)bump((size_t)N * 64 * 4);
    ushort* Wb       = (ushort*)bump((size_t)D * 384 * 2);
    (void)ws_size;

    hipMemsetAsync(gCursor, 0, (size_t)NBMAX * 4, stream);

    const int nbin = (E + CH - 1) / CH;                // 391
    const int npre = (N * 64 + TPB - 1) / TPB;         // 25000
    const int nwcv = (D * 384 / 4 + TPB - 1) / TPB;    // 48
    mega_kernel<<<nbin + npre + nwcv, TPB, 0, stream>>>(
        src, dst, gCursor, tmp, feat, featb, W, Wb, E, N, nbin, npre);

    bucket_csr_kernel<<<NB, CSR_TPB, 0, stream>>>(tmp, gCursor, rsdeg, norm, csr, N);

    const int spmm_blocks = (N * 64 + TPB - 1) / TPB;  // 1 wave per node
    spmm_kernel<<<spmm_blocks, TPB, 0, stream>>>((const uint4*)featb, rsdeg, csr, norm, h1b, N);
    spmm_kernel<<<spmm_blocks, TPB, 0, stream>>>((const uint4*)h1b, rsdeg, csr, norm, h2b, N);

    const int ntiles = (N + 15) / 16;                  // 6250
    gemm_mfma_kernel<<<GEMM_GRID, TPB, 0, stream>>>(
        (const ushort*)featb, (const ushort*)h1b, (const ushort*)h2b,
        Wb, bias, out, N, ntiles);
}